// Round 5
// baseline (261.194 us; speedup 1.0000x reference)
//
#include <hip/hip_runtime.h>
#include <stdint.h>

#define N_NODES 50000
#define CIN 128
#define CMID 128
#define COUT 32
#define KNB 27
#define EPSV 1e-5f

typedef __attribute__((ext_vector_type(4))) float f4v;
typedef __attribute__((ext_vector_type(8))) short s8v;
typedef __attribute__((ext_vector_type(4))) short s4v;

__device__ __forceinline__ unsigned short f2bf(float f) {
  union { float f; uint32_t u; } v; v.f = f;
  return (unsigned short)((v.u + 0x7FFFu + ((v.u >> 16) & 1u)) >> 16);  // RNE
}

__device__ __forceinline__ f4v mfma16(s8v a, s8v b, f4v c) {
  return __builtin_amdgcn_mfma_f32_16x16x32_bf16(a, b, c, 0, 0, 0);
}

// async global->LDS, 16B/lane; dest wave-uniform base + lane*16, src per-lane.
__device__ __forceinline__ void gload_lds16(const void* g, void* lds) {
  __builtin_amdgcn_global_load_lds(
      (const __attribute__((address_space(1))) uint32_t*)(uintptr_t)g,
      (__attribute__((address_space(3))) uint32_t*)(uint32_t)(uintptr_t)lds,
      16, 0, 0);
}

#define SBAR() __builtin_amdgcn_sched_barrier(0)

// ---------------------------------------------------------------- flag ------
__global__ void k_flag(const int* __restrict__ neigh_raw, int* __restrict__ flag) {
  if (threadIdx.x == 0) {
    int ok = 1;
    for (int i = 0; i < 16; ++i) {
      int hi = neigh_raw[2 * i + 1];
      if (hi != 0 && hi != -1) ok = 0;
    }
    *flag = ok;   // 1 => neigh is int64
  }
}

// ---------------------------------------------------------------- transpose -
__global__ __launch_bounds__(256) void k_transpose(
    const void* __restrict__ neigh, int* __restrict__ neighT,
    const int* __restrict__ flag)
{
  __shared__ int tT[KNB][257];
  const int r0 = blockIdx.x * 256;
  const bool is64 = (*flag != 0);
  const int tid = threadIdx.x;
  for (int e = tid; e < 256 * KNB; e += 256) {
    int r = e / KNB, k = e - r * KNB;
    if (r0 + r < N_NODES) {
      long long v = is64 ? ((const long long*)neigh)[(size_t)r0 * KNB + e]
                         : (long long)((const int*)neigh)[(size_t)r0 * KNB + e];
      tT[k][r] = (v < 0) ? N_NODES : (int)v;
    }
  }
  __syncthreads();
  for (int e = tid; e < KNB * 256; e += 256) {
    int k = e >> 8, r = e & 255;
    if (r0 + r < N_NODES) neighT[(size_t)k * N_NODES + r0 + r] = tT[k][r];
  }
}

// ---------------------------------------------------------------- prep ------
// xb[(N+1)][128] bf16 (row N zeros); wt1f/wt2f in MFMA B-fragment order:
//   wt1f chunk ((k*4+kc)*8+n)*64+l = 8 bf16 {W1[k][kc*32+(l>>4)*8+e][n*16+(l&15)]}
//   wt2f chunk ((k*4+kc)*2+n)*64+l = 8 bf16 {W2[k][kc*32+(l>>4)*8+e][n*16+(l&15)]}
__global__ __launch_bounds__(256) void k_prep(
    const float* __restrict__ data, const float* __restrict__ W1,
    const float* __restrict__ W2,
    short* __restrict__ xb, short* __restrict__ wt1f, short* __restrict__ wt2f,
    float* __restrict__ gsums)
{
  const int TOT0 = (N_NODES + 1) * (CIN / 4);
  const int TOTW1 = KNB * 4 * 8 * 64;
  const int TOTW2 = KNB * 4 * 2 * 64;
  int gtid = blockIdx.x * 256 + threadIdx.x;
  int stride = gridDim.x * 256;
  for (int i = gtid; i < TOT0 + TOTW1 + TOTW2; i += stride) {
    if (i < TOT0) {
      int row = i >> 5, c4 = i & 31;
      s4v o = {};
      if (row < N_NODES) {
        f4v v = *(const f4v*)(data + (size_t)row * CIN + c4 * 4);
        o[0] = (short)f2bf(v[0]); o[1] = (short)f2bf(v[1]);
        o[2] = (short)f2bf(v[2]); o[3] = (short)f2bf(v[3]);
      }
      *(s4v*)(xb + (size_t)row * CIN + c4 * 4) = o;
    } else if (i < TOT0 + TOTW1) {
      int c = i - TOT0;
      int k = c >> 11, rem = c & 2047;
      int kc = rem >> 9, rem2 = rem & 511;
      int n = rem2 >> 6, l = rem2 & 63;
      int cin0 = kc * 32 + (l >> 4) * 8, cout = n * 16 + (l & 15);
      s8v o;
#pragma unroll
      for (int e = 0; e < 8; ++e)
        o[e] = (short)f2bf(W1[(size_t)k * (CIN * CMID) + (cin0 + e) * CMID + cout]);
      *(s8v*)(wt1f + (size_t)c * 8) = o;
    } else {
      int c = i - TOT0 - TOTW1;
      int k = c >> 9, rem = c & 511;
      int kc = rem >> 7, rem2 = rem & 127;
      int n = rem2 >> 6, l = rem2 & 63;
      int cin0 = kc * 32 + (l >> 4) * 8, cout = n * 16 + (l & 15);
      s8v o;
#pragma unroll
      for (int e = 0; e < 8; ++e)
        o[e] = (short)f2bf(W2[(size_t)k * (CMID * COUT) + (cin0 + e) * COUT + cout]);
      *(s8v*)(wt2f + (size_t)c * 8) = o;
    }
  }
  if (gtid < 64) gsums[gtid] = 0.0f;
}

// ---------------------------------------------------------------- conv1 -----
// M_block=128, 4 waves (wave = 32 rows x 128 cols), BK=64, kh-split 2.
// B: LDS dbuf via global_load_lds. A: gathered DIRECTLY to fragment regs,
// one step ahead; idx one k ahead. Counted vmcnt(4) + raw s_barrier: A-gathers
// stay in flight across the barrier (only stageB must be drained).
__global__ __launch_bounds__(256, 3) void k_conv1(
    const short* __restrict__ xb, const int* __restrict__ neighT,
    const short* __restrict__ wt1f, short* __restrict__ x1p)
{
  __shared__ short Bs[2][8192];        // 2 x 16KB
  const int tid = threadIdx.x;
  const int l = tid & 63, w = tid >> 6;
  const int bx = blockIdx.x;
  const int kh = (bx >= 391) ? 1 : 0;
  const int rb = kh ? bx - 391 : bx;
  const int rw = rb * 128 + w * 32;
  const int k0 = kh ? 13 : 0, k1 = kh ? 27 : 13;
  const int S = 2 * (k1 - k0);
  const int lr = l & 15, lho = l >> 4;

  int ra = rw + lr;       if (ra >= N_NODES) ra = N_NODES - 1;
  int rb2 = rw + 16 + lr; if (rb2 >= N_NODES) rb2 = N_NODES - 1;

  f4v acc[2][8] = {};
  s8v Ac[2][2], An[2][2];   // [rowset][kc2]
  int ia, ib, ia2 = 0, ib2 = 0;

  auto stageB = [&](int buf, int s) {
    int k = k0 + (s >> 1), h = s & 1;
    const short* src = wt1f + (size_t)((k * 4 + h * 2) * 8) * 512 + l * 8;
#pragma unroll
    for (int j = 0; j < 4; ++j)
      gload_lds16(src + (w * 4 + j) * 512, &Bs[buf][(w * 4 + j) * 512]);
  };
  auto gatherA = [&](s8v A[2][2], int i0, int i1, int h) {
    const short* p0 = xb + (size_t)i0 * CIN + h * 64 + lho * 8;
    const short* p1 = xb + (size_t)i1 * CIN + h * 64 + lho * 8;
#pragma unroll
    for (int kc = 0; kc < 2; ++kc) {
      A[0][kc] = *(const s8v*)(p0 + kc * 32);
      A[1][kc] = *(const s8v*)(p1 + kc * 32);
    }
  };
  auto compute = [&](int cb, s8v A[2][2]) {
#pragma unroll
    for (int kc = 0; kc < 2; ++kc) {
#pragma unroll
      for (int n = 0; n < 8; ++n) {
        s8v bf = *(const s8v*)&Bs[cb][(kc * 8 + n) * 512 + l * 8];
        acc[0][n] = mfma16(A[0][kc], bf, acc[0][n]);
        acc[1][n] = mfma16(A[1][kc], bf, acc[1][n]);
      }
    }
  };

  // prologue
  ia = neighT[(size_t)k0 * N_NODES + ra];
  ib = neighT[(size_t)k0 * N_NODES + rb2];
  stageB(0, 0);
  gatherA(Ac, ia, ib, 0);
  __syncthreads();           // full drain once

  int cur = 0;
  for (int s = 0; s < S; ++s) {
    const int h = s & 1, k = k0 + (s >> 1);
    if (s + 1 < S) stageB(cur ^ 1, s + 1);            // 4 gload_lds
    SBAR();
    if (h == 0 && k + 1 < k1) {                       // idx for next k (2 loads)
      ia2 = neighT[(size_t)(k + 1) * N_NODES + ra];
      ib2 = neighT[(size_t)(k + 1) * N_NODES + rb2];
    }
    SBAR();
    if (s + 1 < S) {                                  // 4 gathers, stay in flight
      if (h == 0) gatherA(An, ia, ib, 1);
      else        gatherA(An, ia2, ib2, 0);
    }
    SBAR();
    compute(cur, Ac);
    asm volatile("s_waitcnt vmcnt(4) lgkmcnt(0)" ::: "memory");
    SBAR();
    __builtin_amdgcn_s_barrier();
    SBAR();
    if (h == 1) { ia = ia2; ib = ib2; }
#pragma unroll
    for (int kc = 0; kc < 2; ++kc) { Ac[0][kc] = An[0][kc]; Ac[1][kc] = An[1][kc]; }
    cur ^= 1;
  }

  short* xp = x1p + (size_t)kh * N_NODES * CMID;
#pragma unroll
  for (int rg = 0; rg < 2; ++rg) {
#pragma unroll
    for (int j = 0; j < 4; ++j) {
      int grow = rw + rg * 16 + lho * 4 + j;
      if (grow < N_NODES) {
#pragma unroll
        for (int n = 0; n < 8; ++n)
          xp[(size_t)grow * CMID + n * 16 + lr] = (short)f2bf(acc[rg][n][j]);
      }
    }
  }
}

// ---------------------------------------------------------------- sum -------
__global__ __launch_bounds__(256) void k_sum(
    const short* __restrict__ x1p, const float* __restrict__ b1,
    float* __restrict__ gsums)
{
  __shared__ float sh[64];
  const int tid = threadIdx.x;
  if (tid < 64) sh[tid] = 0.0f;
  __syncthreads();
  const int g = tid & 31;
  const short* p0 = x1p;
  const short* p1 = x1p + (size_t)N_NODES * CMID;
  f4v bv = *(const f4v*)(b1 + g * 4);
  float s = 0.f, ss = 0.f;
  for (int r = blockIdx.x * 8 + (tid >> 5); r < N_NODES; r += gridDim.x * 8) {
    s4v v0 = *(const s4v*)(p0 + (size_t)r * CMID + g * 4);
    s4v v1 = *(const s4v*)(p1 + (size_t)r * CMID + g * 4);
#pragma unroll
    for (int e = 0; e < 4; ++e) {
      float x = __uint_as_float(((uint32_t)(uint16_t)v0[e]) << 16) +
                __uint_as_float(((uint32_t)(uint16_t)v1[e]) << 16) + bv[e];
      s += x; ss += x * x;
    }
  }
  s += __shfl_xor(s, 32); ss += __shfl_xor(ss, 32);
  if ((tid & 32) == 0) { atomicAdd(&sh[g], s); atomicAdd(&sh[32 + g], ss); }
  __syncthreads();
  if (tid < 64) atomicAdd(&gsums[tid], sh[tid]);
}

// ---------------------------------------------------------------- GN+SiLU ---
__global__ __launch_bounds__(256) void k_gnsilu(
    const short* __restrict__ x1p, const float* __restrict__ b1,
    const float* __restrict__ gsums, const float* __restrict__ gn_w,
    const float* __restrict__ gn_b, short* __restrict__ xnb)
{
  const float invc = 1.0f / (N_NODES * 4.0f);
  const short* p0 = x1p;
  const short* p1 = x1p + (size_t)N_NODES * CMID;
  int gtid = blockIdx.x * 256 + threadIdx.x;
  int stride = gridDim.x * 256;
  const int TOT = (N_NODES + 1) * (CMID / 4);
  for (int i = gtid; i < TOT; i += stride) {
    int row = i >> 5, g = i & 31;
    s4v o = {};
    if (row < N_NODES) {
      float mean = gsums[g] * invc;
      float var = gsums[32 + g] * invc - mean * mean;
      float rs = rsqrtf(var + EPSV);
      s4v v0 = *(const s4v*)(p0 + (size_t)row * CMID + g * 4);
      s4v v1 = *(const s4v*)(p1 + (size_t)row * CMID + g * 4);
      f4v bv = *(const f4v*)(b1 + g * 4);
      f4v wv = *(const f4v*)(gn_w + g * 4);
      f4v gv = *(const f4v*)(gn_b + g * 4);
#pragma unroll
      for (int e = 0; e < 4; ++e) {
        float x = __uint_as_float(((uint32_t)(uint16_t)v0[e]) << 16) +
                  __uint_as_float(((uint32_t)(uint16_t)v1[e]) << 16) + bv[e];
        float xn = (x - mean) * rs * wv[e] + gv[e];
        float y = xn / (1.0f + __expf(-xn));
        o[e] = (short)f2bf(y);
      }
    }
    *(s4v*)(xnb + (size_t)row * CMID + g * 4) = o;
  }
}

// ---------------------------------------------------------------- conv2 -----
// Same counted-vmcnt template. BK=128 (one k per step), wave = 32 rows x 32.
// idx two steps ahead; vmcnt(8) keeps the 8 A-gathers in flight.
__global__ __launch_bounds__(256, 4) void k_conv2(
    const short* __restrict__ xnb, const int* __restrict__ neighT,
    const short* __restrict__ wt2f, float* __restrict__ x2p)
{
  __shared__ short Bs[2][4096];        // 2 x 8KB
  const int tid = threadIdx.x;
  const int l = tid & 63, w = tid >> 6;
  const int bx = blockIdx.x;
  const int kh = (bx >= 391) ? 1 : 0;
  const int rb = kh ? bx - 391 : bx;
  const int rw = rb * 128 + w * 32;
  const int k0 = kh ? 13 : 0, k1 = kh ? 27 : 13;
  const int S = k1 - k0;
  const int lr = l & 15, lho = l >> 4;

  int ra = rw + lr;       if (ra >= N_NODES) ra = N_NODES - 1;
  int rb2 = rw + 16 + lr; if (rb2 >= N_NODES) rb2 = N_NODES - 1;

  f4v acc[2][2] = {};
  s8v Ac[2][4], An[2][4];   // [rowset][kc]
  int ian = 0, ibn = 0, ia2 = 0, ib2 = 0;

  auto stageB = [&](int buf, int k) {
    const short* src = wt2f + (size_t)(k * 8) * 512 + l * 8;
#pragma unroll
    for (int j = 0; j < 2; ++j)
      gload_lds16(src + (w * 2 + j) * 512, &Bs[buf][(w * 2 + j) * 512]);
  };
  auto gatherA = [&](s8v A[2][4], int i0, int i1) {
    const short* p0 = xnb + (size_t)i0 * CMID + lho * 8;
    const short* p1 = xnb + (size_t)i1 * CMID + lho * 8;
#pragma unroll
    for (int kc = 0; kc < 4; ++kc) {
      A[0][kc] = *(const s8v*)(p0 + kc * 32);
      A[1][kc] = *(const s8v*)(p1 + kc * 32);
    }
  };
  auto compute = [&](int cb, s8v A[2][4]) {
#pragma unroll
    for (int kc = 0; kc < 4; ++kc) {
#pragma unroll
      for (int n = 0; n < 2; ++n) {
        s8v bf = *(const s8v*)&Bs[cb][(kc * 2 + n) * 512 + l * 8];
        acc[0][n] = mfma16(A[0][kc], bf, acc[0][n]);
        acc[1][n] = mfma16(A[1][kc], bf, acc[1][n]);
      }
    }
  };

  // prologue: idx(k0), idx(k0+1), stage+gather k0
  int iac = neighT[(size_t)k0 * N_NODES + ra];
  int ibc = neighT[(size_t)k0 * N_NODES + rb2];
  if (S > 1) {
    ian = neighT[(size_t)(k0 + 1) * N_NODES + ra];
    ibn = neighT[(size_t)(k0 + 1) * N_NODES + rb2];
  }
  stageB(0, k0);
  gatherA(Ac, iac, ibc);
  __syncthreads();

  int cur = 0;
  for (int s = 0; s < S; ++s) {
    const int k = k0 + s;
    if (s + 1 < S) stageB(cur ^ 1, k + 1);            // 2 gload_lds
    SBAR();
    if (s + 2 < S) {                                  // idx(k+2): 2 loads
      ia2 = neighT[(size_t)(k + 2) * N_NODES + ra];
      ib2 = neighT[(size_t)(k + 2) * N_NODES + rb2];
    }
    SBAR();
    if (s + 1 < S) gatherA(An, ian, ibn);             // 8 gathers in flight
    SBAR();
    compute(cur, Ac);
    asm volatile("s_waitcnt vmcnt(8) lgkmcnt(0)" ::: "memory");
    SBAR();
    __builtin_amdgcn_s_barrier();
    SBAR();
    ian = ia2; ibn = ib2;
#pragma unroll
    for (int kc = 0; kc < 4; ++kc) { Ac[0][kc] = An[0][kc]; Ac[1][kc] = An[1][kc]; }
    cur ^= 1;
  }

  float* xp = x2p + (size_t)kh * N_NODES * COUT;
#pragma unroll
  for (int rg = 0; rg < 2; ++rg) {
#pragma unroll
    for (int j = 0; j < 4; ++j) {
      int grow = rw + rg * 16 + lho * 4 + j;
      if (grow < N_NODES) {
#pragma unroll
        for (int n = 0; n < 2; ++n)
          xp[(size_t)grow * COUT + n * 16 + lr] = acc[rg][n][j];
      }
    }
  }
}

// ---------------------------------------------------------------- fin -------
__global__ __launch_bounds__(256) void k_fin(
    const float* __restrict__ x2p, const float* __restrict__ b2,
    float* __restrict__ out)
{
  int i = blockIdx.x * 256 + threadIdx.x;
  const int TOT = N_NODES * COUT / 4;
  if (i < TOT) {
    int c4 = i & 7;
    f4v a = *(const f4v*)(x2p + (size_t)i * 4);
    f4v b = *(const f4v*)(x2p + (size_t)N_NODES * COUT + (size_t)i * 4);
    f4v bias = *(const f4v*)(b2 + c4 * 4);
    f4v o = a + b + bias;
    *(f4v*)(out + (size_t)i * 4) = o;
  }
}

// ---------------------------------------------------------------- launch ----
extern "C" void kernel_launch(void* const* d_in, const int* in_sizes, int n_in,
                              void* d_out, int out_size, void* d_ws, size_t ws_size,
                              hipStream_t stream) {
  const float* data = (const float*)d_in[0];
  const void* neigh = d_in[1];
  const float* W1   = (const float*)d_in[2];
  const float* b1   = (const float*)d_in[3];
  const float* gn_w = (const float*)d_in[4];
  const float* gn_b = (const float*)d_in[5];
  const float* W2   = (const float*)d_in[6];
  const float* b2   = (const float*)d_in[7];

  char* p = (char*)d_ws;
  short* xb   = (short*)p; p += (size_t)(N_NODES + 1) * CIN * 2;   // 12.8MB
  float* x2p  = (float*)xb;                 // alias: xb dead before conv2
  short* wt1f = (short*)p; p += (size_t)KNB * CMID * CIN * 2;      // 884KB
  short* wt2f = (short*)p; p += (size_t)KNB * COUT * CMID * 2;     // 221KB
  short* x1p  = (short*)p; p += (size_t)2 * N_NODES * CMID * 2;    // 25.6MB
  short* xnb  = (short*)p; p += (size_t)(N_NODES + 1) * CMID * 2;  // 12.8MB
  int*   neighT = (int*)p; p += (size_t)KNB * N_NODES * 4;         // 5.4MB
  float* gsums = (float*)p;
  int* flag = (int*)(gsums + 64);

  k_flag<<<1, 64, 0, stream>>>((const int*)neigh, flag);
  k_transpose<<<(N_NODES + 255) / 256, 256, 0, stream>>>(neigh, neighT, flag);
  k_prep<<<2048, 256, 0, stream>>>(data, W1, W2, xb, wt1f, wt2f, gsums);
  k_conv1<<<782, 256, 0, stream>>>(xb, neighT, wt1f, x1p);
  k_sum<<<391, 256, 0, stream>>>(x1p, b1, gsums);
  k_gnsilu<<<2048, 256, 0, stream>>>(x1p, b1, gsums, gn_w, gn_b, xnb);
  k_conv2<<<782, 256, 0, stream>>>(xnb, neighT, wt2f, x2p);
  k_fin<<<(N_NODES * COUT / 4 + 255) / 256, 256, 0, stream>>>(x2p, b2, (float*)d_out);
}

// Round 6
// 254.882 us; speedup vs baseline: 1.0248x; 1.0248x over previous
//
#include <hip/hip_runtime.h>
#include <stdint.h>

#define N_NODES 50000
#define CIN 128
#define CMID 128
#define COUT 32
#define KNB 27
#define EPSV 1e-5f

typedef __attribute__((ext_vector_type(4))) float f4v;
typedef __attribute__((ext_vector_type(8))) short s8v;
typedef __attribute__((ext_vector_type(4))) short s4v;

__device__ __forceinline__ unsigned short f2bf(float f) {
  union { float f; uint32_t u; } v; v.f = f;
  return (unsigned short)((v.u + 0x7FFFu + ((v.u >> 16) & 1u)) >> 16);  // RNE
}

__device__ __forceinline__ f4v mfma16(s8v a, s8v b, f4v c) {
  return __builtin_amdgcn_mfma_f32_16x16x32_bf16(a, b, c, 0, 0, 0);
}

// async global->LDS, 16B/lane; dest wave-uniform base + lane*16, src per-lane.
__device__ __forceinline__ void gload_lds16(const void* g, void* lds) {
  __builtin_amdgcn_global_load_lds(
      (const __attribute__((address_space(1))) uint32_t*)(uintptr_t)g,
      (__attribute__((address_space(3))) uint32_t*)(uint32_t)(uintptr_t)lds,
      16, 0, 0);
}

// inline int64-vs-int32 detection (hi words of first 16 entries all 0/-1)
__device__ __forceinline__ bool neigh_is64(const void* neigh) {
  const int* p = (const int*)neigh;
  int ok = 1;
#pragma unroll
  for (int i = 0; i < 16; ++i) {
    int hi = p[2 * i + 1];
    if (hi != 0 && hi != -1) ok = 0;
  }
  return ok != 0;
}

// ---------------------------------------------------------------- transpose -
// neighT[k][row] int32 (empty -> N_NODES), via LDS tile transpose (coalesced).
__global__ __launch_bounds__(256) void k_transpose(
    const void* __restrict__ neigh, int* __restrict__ neighT)
{
  __shared__ int tT[KNB][257];
  const int r0 = blockIdx.x * 256;
  const bool is64 = neigh_is64(neigh);
  const int tid = threadIdx.x;
  for (int e = tid; e < 256 * KNB; e += 256) {
    int r = e / KNB, k = e - r * KNB;
    if (r0 + r < N_NODES) {
      long long v = is64 ? ((const long long*)neigh)[(size_t)r0 * KNB + e]
                         : (long long)((const int*)neigh)[(size_t)r0 * KNB + e];
      tT[k][r] = (v < 0) ? N_NODES : (int)v;
    }
  }
  __syncthreads();
  for (int e = tid; e < KNB * 256; e += 256) {
    int k = e >> 8, r = e & 255;
    if (r0 + r < N_NODES) neighT[(size_t)k * N_NODES + r0 + r] = tT[k][r];
  }
}

// ---------------------------------------------------------------- prep ------
// xb[(N+1)][128] bf16 (row N zeros); wt1f/wt2f in MFMA B-fragment order:
//   wt1f chunk ((k*4+kc)*8+n)*64+l = 8 bf16 {W1[k][kc*32+(l>>4)*8+e][n*16+(l&15)]}
//   wt2f chunk ((k*4+kc)*2+n)*64+l = 8 bf16 {W2[k][kc*32+(l>>4)*8+e][n*16+(l&15)]}
__global__ __launch_bounds__(256) void k_prep(
    const float* __restrict__ data, const float* __restrict__ W1,
    const float* __restrict__ W2,
    short* __restrict__ xb, short* __restrict__ wt1f, short* __restrict__ wt2f,
    float* __restrict__ gsums)
{
  const int TOT0 = (N_NODES + 1) * (CIN / 4);
  const int TOTW1 = KNB * 4 * 8 * 64;
  const int TOTW2 = KNB * 4 * 2 * 64;
  int gtid = blockIdx.x * 256 + threadIdx.x;
  int stride = gridDim.x * 256;
  for (int i = gtid; i < TOT0 + TOTW1 + TOTW2; i += stride) {
    if (i < TOT0) {
      int row = i >> 5, c4 = i & 31;
      s4v o = {};
      if (row < N_NODES) {
        f4v v = *(const f4v*)(data + (size_t)row * CIN + c4 * 4);
        o[0] = (short)f2bf(v[0]); o[1] = (short)f2bf(v[1]);
        o[2] = (short)f2bf(v[2]); o[3] = (short)f2bf(v[3]);
      }
      *(s4v*)(xb + (size_t)row * CIN + c4 * 4) = o;
    } else if (i < TOT0 + TOTW1) {
      int c = i - TOT0;
      int k = c >> 11, rem = c & 2047;
      int kc = rem >> 9, rem2 = rem & 511;
      int n = rem2 >> 6, l = rem2 & 63;
      int cin0 = kc * 32 + (l >> 4) * 8, cout = n * 16 + (l & 15);
      s8v o;
#pragma unroll
      for (int e = 0; e < 8; ++e)
        o[e] = (short)f2bf(W1[(size_t)k * (CIN * CMID) + (cin0 + e) * CMID + cout]);
      *(s8v*)(wt1f + (size_t)c * 8) = o;
    } else {
      int c = i - TOT0 - TOTW1;
      int k = c >> 9, rem = c & 511;
      int kc = rem >> 7, rem2 = rem & 127;
      int n = rem2 >> 6, l = rem2 & 63;
      int cin0 = kc * 32 + (l >> 4) * 8, cout = n * 16 + (l & 15);
      s8v o;
#pragma unroll
      for (int e = 0; e < 8; ++e)
        o[e] = (short)f2bf(W2[(size_t)k * (CMID * COUT) + (cin0 + e) * COUT + cout]);
      *(s8v*)(wt2f + (size_t)c * 8) = o;
    }
  }
  if (gtid < 64) gsums[gtid] = 0.0f;
}

// ---------------------------------------------------------------- conv1 -----
// M_block=128, 4 waves (wave = 32 rows x 128 cols), BK=64, kh-split 2.
// B: LDS dbuf via global_load_lds. A: gathered DIRECTLY to fragment regs one
// step ahead; idx one k ahead. Plain __syncthreads per step; NO scheduling
// pins — compiler manages waitcnts and register-level pipelining.
__global__ __launch_bounds__(256, 3) void k_conv1(
    const short* __restrict__ xb, const int* __restrict__ neighT,
    const short* __restrict__ wt1f, short* __restrict__ x1p)
{
  __shared__ short Bs[2][8192];        // 2 x 16KB
  const int tid = threadIdx.x;
  const int l = tid & 63, w = tid >> 6;
  const int bx = blockIdx.x;
  const int kh = (bx >= 391) ? 1 : 0;
  const int rb = kh ? bx - 391 : bx;
  const int rw = rb * 128 + w * 32;
  const int k0 = kh ? 13 : 0, k1 = kh ? 27 : 13;
  const int S = 2 * (k1 - k0);
  const int lr = l & 15, lho = l >> 4;

  int ra = rw + lr;       if (ra >= N_NODES) ra = N_NODES - 1;
  int rb2 = rw + 16 + lr; if (rb2 >= N_NODES) rb2 = N_NODES - 1;

  f4v acc[2][8] = {};
  s8v Ac[2][2], An[2][2];   // [rowset][kc2]
  int ia, ib, ia2 = 0, ib2 = 0;

  auto stageB = [&](int buf, int s) {
    int k = k0 + (s >> 1), h = s & 1;
    const short* src = wt1f + (size_t)((k * 4 + h * 2) * 8) * 512 + l * 8;
#pragma unroll
    for (int j = 0; j < 4; ++j)
      gload_lds16(src + (w * 4 + j) * 512, &Bs[buf][(w * 4 + j) * 512]);
  };
  auto gatherA = [&](s8v A[2][2], int i0, int i1, int h) {
    const short* p0 = xb + (size_t)i0 * CIN + h * 64 + lho * 8;
    const short* p1 = xb + (size_t)i1 * CIN + h * 64 + lho * 8;
#pragma unroll
    for (int kc = 0; kc < 2; ++kc) {
      A[0][kc] = *(const s8v*)(p0 + kc * 32);
      A[1][kc] = *(const s8v*)(p1 + kc * 32);
    }
  };
  auto compute = [&](int cb, s8v A[2][2]) {
#pragma unroll
    for (int kc = 0; kc < 2; ++kc) {
#pragma unroll
      for (int n = 0; n < 8; ++n) {
        s8v bf = *(const s8v*)&Bs[cb][(kc * 8 + n) * 512 + l * 8];
        acc[0][n] = mfma16(A[0][kc], bf, acc[0][n]);
        acc[1][n] = mfma16(A[1][kc], bf, acc[1][n]);
      }
    }
  };

  // prologue
  ia = neighT[(size_t)k0 * N_NODES + ra];
  ib = neighT[(size_t)k0 * N_NODES + rb2];
  stageB(0, 0);
  gatherA(Ac, ia, ib, 0);
  __syncthreads();

  int cur = 0;
  for (int s = 0; s < S; ++s) {
    const int h = s & 1, k = k0 + (s >> 1);
    if (s + 1 < S) stageB(cur ^ 1, s + 1);            // next-step B (async LDS)
    if (h == 0 && k + 1 < k1) {                       // idx for next k
      ia2 = neighT[(size_t)(k + 1) * N_NODES + ra];
      ib2 = neighT[(size_t)(k + 1) * N_NODES + rb2];
    }
    if (s + 1 < S) {                                  // next-step A gathers
      if (h == 0) gatherA(An, ia, ib, 1);
      else        gatherA(An, ia2, ib2, 0);
    }
    compute(cur, Ac);
    __syncthreads();
    if (h == 1) { ia = ia2; ib = ib2; }
#pragma unroll
    for (int kc = 0; kc < 2; ++kc) { Ac[0][kc] = An[0][kc]; Ac[1][kc] = An[1][kc]; }
    cur ^= 1;
  }

  short* xp = x1p + (size_t)kh * N_NODES * CMID;
#pragma unroll
  for (int rg = 0; rg < 2; ++rg) {
#pragma unroll
    for (int j = 0; j < 4; ++j) {
      int grow = rw + rg * 16 + lho * 4 + j;
      if (grow < N_NODES) {
#pragma unroll
        for (int n = 0; n < 8; ++n)
          xp[(size_t)grow * CMID + n * 16 + lr] = (short)f2bf(acc[rg][n][j]);
      }
    }
  }
}

// ---------------------------------------------------------------- sum -------
__global__ __launch_bounds__(256) void k_sum(
    const short* __restrict__ x1p, const float* __restrict__ b1,
    float* __restrict__ gsums)
{
  __shared__ float sh[64];
  const int tid = threadIdx.x;
  if (tid < 64) sh[tid] = 0.0f;
  __syncthreads();
  const int g = tid & 31;
  const short* p0 = x1p;
  const short* p1 = x1p + (size_t)N_NODES * CMID;
  f4v bv = *(const f4v*)(b1 + g * 4);
  float s = 0.f, ss = 0.f;
  for (int r = blockIdx.x * 8 + (tid >> 5); r < N_NODES; r += gridDim.x * 8) {
    s4v v0 = *(const s4v*)(p0 + (size_t)r * CMID + g * 4);
    s4v v1 = *(const s4v*)(p1 + (size_t)r * CMID + g * 4);
#pragma unroll
    for (int e = 0; e < 4; ++e) {
      float x = __uint_as_float(((uint32_t)(uint16_t)v0[e]) << 16) +
                __uint_as_float(((uint32_t)(uint16_t)v1[e]) << 16) + bv[e];
      s += x; ss += x * x;
    }
  }
  s += __shfl_xor(s, 32); ss += __shfl_xor(ss, 32);
  if ((tid & 32) == 0) { atomicAdd(&sh[g], s); atomicAdd(&sh[32 + g], ss); }
  __syncthreads();
  if (tid < 64) atomicAdd(&gsums[tid], sh[tid]);
}

// ---------------------------------------------------------------- GN+SiLU ---
__global__ __launch_bounds__(256) void k_gnsilu(
    const short* __restrict__ x1p, const float* __restrict__ b1,
    const float* __restrict__ gsums, const float* __restrict__ gn_w,
    const float* __restrict__ gn_b, short* __restrict__ xnb)
{
  const float invc = 1.0f / (N_NODES * 4.0f);
  const short* p0 = x1p;
  const short* p1 = x1p + (size_t)N_NODES * CMID;
  int gtid = blockIdx.x * 256 + threadIdx.x;
  int stride = gridDim.x * 256;
  const int TOT = (N_NODES + 1) * (CMID / 4);
  for (int i = gtid; i < TOT; i += stride) {
    int row = i >> 5, g = i & 31;
    s4v o = {};
    if (row < N_NODES) {
      float mean = gsums[g] * invc;
      float var = gsums[32 + g] * invc - mean * mean;
      float rs = rsqrtf(var + EPSV);
      s4v v0 = *(const s4v*)(p0 + (size_t)row * CMID + g * 4);
      s4v v1 = *(const s4v*)(p1 + (size_t)row * CMID + g * 4);
      f4v bv = *(const f4v*)(b1 + g * 4);
      f4v wv = *(const f4v*)(gn_w + g * 4);
      f4v gv = *(const f4v*)(gn_b + g * 4);
#pragma unroll
      for (int e = 0; e < 4; ++e) {
        float x = __uint_as_float(((uint32_t)(uint16_t)v0[e]) << 16) +
                  __uint_as_float(((uint32_t)(uint16_t)v1[e]) << 16) + bv[e];
        float xn = (x - mean) * rs * wv[e] + gv[e];
        float y = xn / (1.0f + __expf(-xn));
        o[e] = (short)f2bf(y);
      }
    }
    *(s4v*)(xnb + (size_t)row * CMID + g * 4) = o;
  }
}

// ---------------------------------------------------------------- conv2 -----
// Same template. BK=128 (one k per step), wave = 32 rows x 32 cols, kh-split.
// idx two steps ahead; plain __syncthreads, no pins.
__global__ __launch_bounds__(256, 4) void k_conv2(
    const short* __restrict__ xnb, const int* __restrict__ neighT,
    const short* __restrict__ wt2f, float* __restrict__ x2p)
{
  __shared__ short Bs[2][4096];        // 2 x 8KB
  const int tid = threadIdx.x;
  const int l = tid & 63, w = tid >> 6;
  const int bx = blockIdx.x;
  const int kh = (bx >= 391) ? 1 : 0;
  const int rb = kh ? bx - 391 : bx;
  const int rw = rb * 128 + w * 32;
  const int k0 = kh ? 13 : 0, k1 = kh ? 27 : 13;
  const int S = k1 - k0;
  const int lr = l & 15, lho = l >> 4;

  int ra = rw + lr;       if (ra >= N_NODES) ra = N_NODES - 1;
  int rb2 = rw + 16 + lr; if (rb2 >= N_NODES) rb2 = N_NODES - 1;

  f4v acc[2][2] = {};
  s8v Ac[2][4], An[2][4];   // [rowset][kc]
  int ian = 0, ibn = 0, ia2 = 0, ib2 = 0;

  auto stageB = [&](int buf, int k) {
    const short* src = wt2f + (size_t)(k * 8) * 512 + l * 8;
#pragma unroll
    for (int j = 0; j < 2; ++j)
      gload_lds16(src + (w * 2 + j) * 512, &Bs[buf][(w * 2 + j) * 512]);
  };
  auto gatherA = [&](s8v A[2][4], int i0, int i1) {
    const short* p0 = xnb + (size_t)i0 * CMID + lho * 8;
    const short* p1 = xnb + (size_t)i1 * CMID + lho * 8;
#pragma unroll
    for (int kc = 0; kc < 4; ++kc) {
      A[0][kc] = *(const s8v*)(p0 + kc * 32);
      A[1][kc] = *(const s8v*)(p1 + kc * 32);
    }
  };
  auto compute = [&](int cb, s8v A[2][4]) {
#pragma unroll
    for (int kc = 0; kc < 4; ++kc) {
#pragma unroll
      for (int n = 0; n < 2; ++n) {
        s8v bf = *(const s8v*)&Bs[cb][(kc * 2 + n) * 512 + l * 8];
        acc[0][n] = mfma16(A[0][kc], bf, acc[0][n]);
        acc[1][n] = mfma16(A[1][kc], bf, acc[1][n]);
      }
    }
  };

  // prologue: idx(k0), idx(k0+1), stage+gather k0
  int iac = neighT[(size_t)k0 * N_NODES + ra];
  int ibc = neighT[(size_t)k0 * N_NODES + rb2];
  if (S > 1) {
    ian = neighT[(size_t)(k0 + 1) * N_NODES + ra];
    ibn = neighT[(size_t)(k0 + 1) * N_NODES + rb2];
  }
  stageB(0, k0);
  gatherA(Ac, iac, ibc);
  __syncthreads();

  int cur = 0;
  for (int s = 0; s < S; ++s) {
    const int k = k0 + s;
    if (s + 1 < S) stageB(cur ^ 1, k + 1);
    if (s + 2 < S) {
      ia2 = neighT[(size_t)(k + 2) * N_NODES + ra];
      ib2 = neighT[(size_t)(k + 2) * N_NODES + rb2];
    }
    if (s + 1 < S) gatherA(An, ian, ibn);
    compute(cur, Ac);
    __syncthreads();
    ian = ia2; ibn = ib2;
#pragma unroll
    for (int kc = 0; kc < 4; ++kc) { Ac[0][kc] = An[0][kc]; Ac[1][kc] = An[1][kc]; }
    cur ^= 1;
  }

  float* xp = x2p + (size_t)kh * N_NODES * COUT;
#pragma unroll
  for (int rg = 0; rg < 2; ++rg) {
#pragma unroll
    for (int j = 0; j < 4; ++j) {
      int grow = rw + rg * 16 + lho * 4 + j;
      if (grow < N_NODES) {
#pragma unroll
        for (int n = 0; n < 2; ++n)
          xp[(size_t)grow * COUT + n * 16 + lr] = acc[rg][n][j];
      }
    }
  }
}

// ---------------------------------------------------------------- fin -------
__global__ __launch_bounds__(256) void k_fin(
    const float* __restrict__ x2p, const float* __restrict__ b2,
    float* __restrict__ out)
{
  int i = blockIdx.x * 256 + threadIdx.x;
  const int TOT = N_NODES * COUT / 4;
  if (i < TOT) {
    int c4 = i & 7;
    f4v a = *(const f4v*)(x2p + (size_t)i * 4);
    f4v b = *(const f4v*)(x2p + (size_t)N_NODES * COUT + (size_t)i * 4);
    f4v bias = *(const f4v*)(b2 + c4 * 4);
    f4v o = a + b + bias;
    *(f4v*)(out + (size_t)i * 4) = o;
  }
}

// ---------------------------------------------------------------- launch ----
extern "C" void kernel_launch(void* const* d_in, const int* in_sizes, int n_in,
                              void* d_out, int out_size, void* d_ws, size_t ws_size,
                              hipStream_t stream) {
  const float* data = (const float*)d_in[0];
  const void* neigh = d_in[1];
  const float* W1   = (const float*)d_in[2];
  const float* b1   = (const float*)d_in[3];
  const float* gn_w = (const float*)d_in[4];
  const float* gn_b = (const float*)d_in[5];
  const float* W2   = (const float*)d_in[6];
  const float* b2   = (const float*)d_in[7];

  char* p = (char*)d_ws;
  short* xb   = (short*)p; p += (size_t)(N_NODES + 1) * CIN * 2;   // 12.8MB
  float* x2p  = (float*)xb;                 // alias: xb dead before conv2
  short* wt1f = (short*)p; p += (size_t)KNB * CMID * CIN * 2;      // 884KB
  short* wt2f = (short*)p; p += (size_t)KNB * COUT * CMID * 2;     // 221KB
  short* x1p  = (short*)p; p += (size_t)2 * N_NODES * CMID * 2;    // 25.6MB
  short* xnb  = (short*)p; p += (size_t)(N_NODES + 1) * CMID * 2;  // 12.8MB
  int*   neighT = (int*)p; p += (size_t)KNB * N_NODES * 4;         // 5.4MB
  float* gsums = (float*)p;

  k_transpose<<<(N_NODES + 255) / 256, 256, 0, stream>>>(neigh, neighT);
  k_prep<<<2048, 256, 0, stream>>>(data, W1, W2, xb, wt1f, wt2f, gsums);
  k_conv1<<<782, 256, 0, stream>>>(xb, neighT, wt1f, x1p);
  k_sum<<<391, 256, 0, stream>>>(x1p, b1, gsums);
  k_gnsilu<<<2048, 256, 0, stream>>>(x1p, b1, gsums, gn_w, gn_b, xnb);
  k_conv2<<<782, 256, 0, stream>>>(xnb, neighT, wt2f, x2p);
  k_fin<<<(N_NODES * COUT / 4 + 255) / 256, 256, 0, stream>>>(x2p, b2, (float*)d_out);
}